// Round 5
// baseline (266.308 us; speedup 1.0000x reference)
//
#include <hip/hip_runtime.h>

// VecInt: scaling-and-squaring integration, vel [2,128,128,128,3] fp32.
// v = vel/2^7; 7x: v = v + warp(v, v)  (border-clipped trilinear).
//
// Round-10: r9 skeleton, batching forced through the DATAFLOW.
// Evidence trail:
//   r6: time ~ 1/resident_waves => latency-bound.
//   r7: gathers L3->L2 (FETCH halved), time flat => epoch count, not tier.
//   r8: source-order batching ignored (VGPR stayed 28).
//   r9: sched_barrier(0) ignored too (VGPR fell to 24!) -- it fences the
//       machine scheduler only; IR passes hoist the pure FMA consumers
//       above the no-mem intrinsic, so load->use were already adjacent.
// Fix: empty asm volatile with ALL gather results as "+v" in/outs between
// loads and consumers. Consumers depend on asm outputs; asm depends on all
// loads; RA must keep the whole batch live => ONE vmcnt wait epoch.
// Zero instructions emitted; the VGPR cost is the point.

#define NVOX_PER_B (1 << 21)          // 128^3
#define NXCD 8

typedef _Float16 h16;
typedef __attribute__((ext_vector_type(4))) _Float16 h16x4;   // 8 bytes
typedef __attribute__((ext_vector_type(8))) _Float16 h16x8;   // 16 bytes
typedef __attribute__((ext_vector_type(4))) float    f32x4;   // 16 bytes

__device__ __forceinline__ int swz_idx()
{
    // chunked XCD swizzle: contiguous 1/8 of the grid per XCD (16384%8==0)
    int nb = gridDim.x;
    int chunk = nb >> 3;
    int bid = blockIdx.x;
    int newbid = (bid & (NXCD - 1)) * chunk + (bid >> 3);
    return newbid * blockDim.x + threadIdx.x;
}

// ---- full 8-corner setup (f32 first pass) ------------------------------
__device__ __forceinline__ void tri_setup(
    int x, int y, int z, float fx, float fy, float fz,
    int* off, float* w)
{
    float lx = fminf(fmaxf((float)x + fx, 0.0f), 127.0f);
    float ly = fminf(fmaxf((float)y + fy, 0.0f), 127.0f);
    float lz = fminf(fmaxf((float)z + fz, 0.0f), 127.0f);

    float flx = floorf(lx), fly = floorf(ly), flz = floorf(lz);
    float wx1 = lx - flx, wy1 = ly - fly, wz1 = lz - flz;
    float wx0 = 1.0f - wx1, wy0 = 1.0f - wy1, wz0 = 1.0f - wz1;

    int x0 = (int)flx, y0 = (int)fly, z0 = (int)flz;
    int x1 = min(x0 + 1, 127);
    int y1 = min(y0 + 1, 127);
    int z1 = min(z0 + 1, 127);

    off[0] = (x0 << 14) + (y0 << 7) + z0;
    off[1] = (x0 << 14) + (y0 << 7) + z1;
    off[2] = (x0 << 14) + (y1 << 7) + z0;
    off[3] = (x0 << 14) + (y1 << 7) + z1;
    off[4] = (x1 << 14) + (y0 << 7) + z0;
    off[5] = (x1 << 14) + (y0 << 7) + z1;
    off[6] = (x1 << 14) + (y1 << 7) + z0;
    off[7] = (x1 << 14) + (y1 << 7) + z1;
    w[0] = wx0 * wy0 * wz0;  w[1] = wx0 * wy0 * wz1;
    w[2] = wx0 * wy1 * wz0;  w[3] = wx0 * wy1 * wz1;
    w[4] = wx1 * wy0 * wz0;  w[5] = wx1 * wy0 * wz1;
    w[6] = wx1 * wy1 * wz0;  w[7] = wx1 * wy1 * wz1;
}

// ---- pair setup (fp16 field passes): 4 (x,y) corners, z handled in-reg --
__device__ __forceinline__ void tri_setup_pair(
    int x, int y, int z, float fx, float fy, float fz,
    int* offp, float* wxy, float& wz0, float& wz1)
{
    float lx = fminf(fmaxf((float)x + fx, 0.0f), 127.0f);
    float ly = fminf(fmaxf((float)y + fy, 0.0f), 127.0f);
    float lz = fminf(fmaxf((float)z + fz, 0.0f), 127.0f);

    float flx = floorf(lx), fly = floorf(ly), flz = floorf(lz);
    float wx1 = lx - flx, wy1 = ly - fly;
    wz1 = lz - flz;                      // == 0 exactly when z0 == 127
    float wx0 = 1.0f - wx1, wy0 = 1.0f - wy1;
    wz0 = 1.0f - wz1;

    int x0 = (int)flx, y0 = (int)fly, z0 = (int)flz;
    int x1 = min(x0 + 1, 127);
    int y1 = min(y0 + 1, 127);

    offp[0] = (x0 << 14) + (y0 << 7) + z0;
    offp[1] = (x0 << 14) + (y1 << 7) + z0;
    offp[2] = (x1 << 14) + (y0 << 7) + z0;
    offp[3] = (x1 << 14) + (y1 << 7) + z0;
    wxy[0] = wx0 * wy0;  wxy[1] = wx0 * wy1;
    wxy[2] = wx1 * wy0;  wxy[3] = wx1 * wy1;
}

// batched 4x dwordx4 pair-gather + reduce; the empty asm is a DATAFLOW
// barrier: consumers depend on its outputs, it depends on all 4 loads =>
// all loads issue before any use, RA holds the batch (one wait epoch).
__device__ __forceinline__ void sample_pairs(
    const h16x4* __restrict__ vb, const int* offp, const float* wxy,
    float wz0, float wz1, float& ox, float& oy, float& oz)
{
    f32x4 q0 = *(const f32x4*)(vb + offp[0]);
    f32x4 q1 = *(const f32x4*)(vb + offp[1]);
    f32x4 q2 = *(const f32x4*)(vb + offp[2]);
    f32x4 q3 = *(const f32x4*)(vb + offp[3]);
    asm volatile("" : "+v"(q0), "+v"(q1), "+v"(q2), "+v"(q3));

    h16x8 c0 = __builtin_bit_cast(h16x8, q0);
    h16x8 c1 = __builtin_bit_cast(h16x8, q1);
    h16x8 c2 = __builtin_bit_cast(h16x8, q2);
    h16x8 c3 = __builtin_bit_cast(h16x8, q3);

    float sx0 = wz0 * (float)c0[0] + wz1 * (float)c0[4];
    float sy0 = wz0 * (float)c0[1] + wz1 * (float)c0[5];
    float sz0 = wz0 * (float)c0[2] + wz1 * (float)c0[6];
    float sx1 = wz0 * (float)c1[0] + wz1 * (float)c1[4];
    float sy1 = wz0 * (float)c1[1] + wz1 * (float)c1[5];
    float sz1 = wz0 * (float)c1[2] + wz1 * (float)c1[6];
    float sx2 = wz0 * (float)c2[0] + wz1 * (float)c2[4];
    float sy2 = wz0 * (float)c2[1] + wz1 * (float)c2[5];
    float sz2 = wz0 * (float)c2[2] + wz1 * (float)c2[6];
    float sx3 = wz0 * (float)c3[0] + wz1 * (float)c3[4];
    float sy3 = wz0 * (float)c3[1] + wz1 * (float)c3[5];
    float sz3 = wz0 * (float)c3[2] + wz1 * (float)c3[6];

    ox = wxy[0] * sx0 + wxy[1] * sx1 + wxy[2] * sx2 + wxy[3] * sx3;
    oy = wxy[0] * sy0 + wxy[1] * sy1 + wxy[2] * sy2 + wxy[3] * sy3;
    oz = wxy[0] * sz0 + wxy[1] * sz1 + wxy[2] * sz2 + wxy[3] * sz3;
}

// ---- step 1: f32 packed vel -> fp16x4 field (fuses the /128 scale) -----
__global__ __launch_bounds__(256, 6) void vecint_first(
    const float* __restrict__ vin, h16x4* __restrict__ vout,
    float scale, int nvox)
{
    int idx = swz_idx();
    if (idx >= nvox) return;

    int z = idx & 127;
    int y = (idx >> 7) & 127;
    int x = (idx >> 14) & 127;
    int b = idx >> 21;

    int base = idx * 3;
    float fx = vin[base + 0] * scale;
    float fy = vin[base + 1] * scale;
    float fz = vin[base + 2] * scale;

    int off[8]; float w[8];
    tri_setup(x, y, z, fx, fy, fz, off, w);

    const float* vb = vin + (size_t)b * (NVOX_PER_B * 3);

    // gather phase: all 24 dword loads, then a DATAFLOW barrier
    float g[24];
#pragma unroll
    for (int i = 0; i < 8; ++i) {
        const float* p = vb + (size_t)off[i] * 3;
        g[i * 3 + 0] = p[0]; g[i * 3 + 1] = p[1]; g[i * 3 + 2] = p[2];
    }
    asm volatile("" :
        "+v"(g[0]),  "+v"(g[1]),  "+v"(g[2]),  "+v"(g[3]),
        "+v"(g[4]),  "+v"(g[5]),  "+v"(g[6]),  "+v"(g[7]),
        "+v"(g[8]),  "+v"(g[9]),  "+v"(g[10]), "+v"(g[11]),
        "+v"(g[12]), "+v"(g[13]), "+v"(g[14]), "+v"(g[15]),
        "+v"(g[16]), "+v"(g[17]), "+v"(g[18]), "+v"(g[19]),
        "+v"(g[20]), "+v"(g[21]), "+v"(g[22]), "+v"(g[23]));

    float ox = 0.0f, oy = 0.0f, oz = 0.0f;
#pragma unroll
    for (int i = 0; i < 8; ++i) {
        ox += w[i] * g[i * 3 + 0];
        oy += w[i] * g[i * 3 + 1];
        oz += w[i] * g[i * 3 + 2];
    }

    h16x4 o;
    o.x = (h16)(fx + scale * ox);
    o.y = (h16)(fy + scale * oy);
    o.z = (h16)(fz + scale * oz);
    o.w = (h16)0.0f;
    vout[idx] = o;
}

// ---- steps 2..6: fp16x4 -> fp16x4 --------------------------------------
__global__ __launch_bounds__(256, 8) void vecint_mid(
    const h16x4* __restrict__ vin, h16x4* __restrict__ vout, int nvox)
{
    int idx = swz_idx();
    if (idx >= nvox) return;

    int z = idx & 127;
    int y = (idx >> 7) & 127;
    int x = (idx >> 14) & 127;
    int b = idx >> 21;

    h16x4 f = vin[idx];
    float fx = (float)f.x, fy = (float)f.y, fz = (float)f.z;

    int offp[4]; float wxy[4], wz0, wz1;
    tri_setup_pair(x, y, z, fx, fy, fz, offp, wxy, wz0, wz1);

    const h16x4* vb = vin + ((size_t)b << 21);
    float ox, oy, oz;
    sample_pairs(vb, offp, wxy, wz0, wz1, ox, oy, oz);

    h16x4 o;
    o.x = (h16)(fx + ox);
    o.y = (h16)(fy + oy);
    o.z = (h16)(fz + oz);
    o.w = (h16)0.0f;
    vout[idx] = o;
}

// ---- step 7: fp16x4 -> f32 packed --------------------------------------
__global__ __launch_bounds__(256, 8) void vecint_last(
    const h16x4* __restrict__ vin, float* __restrict__ vout, int nvox)
{
    int idx = swz_idx();
    if (idx >= nvox) return;

    int z = idx & 127;
    int y = (idx >> 7) & 127;
    int x = (idx >> 14) & 127;
    int b = idx >> 21;

    h16x4 f = vin[idx];
    float fx = (float)f.x, fy = (float)f.y, fz = (float)f.z;

    int offp[4]; float wxy[4], wz0, wz1;
    tri_setup_pair(x, y, z, fx, fy, fz, offp, wxy, wz0, wz1);

    const h16x4* vb = vin + ((size_t)b << 21);
    float ox, oy, oz;
    sample_pairs(vb, offp, wxy, wz0, wz1, ox, oy, oz);

    int base = idx * 3;
    vout[base + 0] = fx + ox;
    vout[base + 1] = fy + oy;
    vout[base + 2] = fz + oz;
}

extern "C" void kernel_launch(void* const* d_in, const int* in_sizes, int n_in,
                              void* d_out, int out_size, void* d_ws, size_t ws_size,
                              hipStream_t stream) {
    const float* vel = (const float*)d_in[0];
    float* out = (float*)d_out;

    int nvox = in_sizes[0] / 3;            // 4,194,304 voxels (2 batches)
    int blocks = (nvox + 255) / 256;       // 16384 (divisible by 8)
    float s0 = 1.0f / 128.0f;              // 1 / 2^INT_STEPS

    // D = fp16 field living in the first 33.5 MB of d_out (d_out is 50.3 MB);
    // W = fp16 field in d_ws.
    h16x4* D = (h16x4*)d_out;
    h16x4* W = (h16x4*)d_ws;

    // zero 16B past each field so the z-pair load's weight-0 hi half can
    // never read NaN bits at the absolute last voxel
    hipMemsetAsync((char*)d_out + (size_t)nvox * 8, 0, 16, stream);
    hipMemsetAsync((char*)d_ws  + (size_t)nvox * 8, 0, 16, stream);

    vecint_first<<<blocks, 256, 0, stream>>>(vel, D, s0, nvox);   // 1: vel->D
    vecint_mid  <<<blocks, 256, 0, stream>>>(D, W, nvox);         // 2: D->W
    vecint_mid  <<<blocks, 256, 0, stream>>>(W, D, nvox);         // 3: W->D
    vecint_mid  <<<blocks, 256, 0, stream>>>(D, W, nvox);         // 4: D->W
    vecint_mid  <<<blocks, 256, 0, stream>>>(W, D, nvox);         // 5: W->D
    vecint_mid  <<<blocks, 256, 0, stream>>>(D, W, nvox);         // 6: D->W
    vecint_last <<<blocks, 256, 0, stream>>>(W, out, nvox);       // 7: W->out (f32)
}